// Round 9
// baseline (101.752 us; speedup 1.0000x reference)
//
#include <hip/hip_runtime.h>

#define HID 128
#define NN  256
#define BB  8
#define NCATS 64

// ---------------------------------------------------------------------------
// bf16 pack/unpack (RNE rounding on pack)
__device__ inline unsigned pack_bf16(float lo, float hi) {
    unsigned ul = __float_as_uint(lo);
    unsigned uh = __float_as_uint(hi);
    ul = (ul + 0x7fffu + ((ul >> 16) & 1u)) >> 16;
    uh = (uh + 0x7fffu + ((uh >> 16) & 1u)) & 0xffff0000u;
    return ul | uh;
}
__device__ inline float bf_lo(unsigned v) { return __uint_as_float(v << 16); }
__device__ inline float bf_hi(unsigned v) { return __uint_as_float(v & 0xffff0000u); }

// Wave-per-row LN reduction (row split as a=dim[lane], c=dim[lane+64]).
__device__ inline void ln_stats(float a, float c, float& mean, float& rs) {
    float s = a + c;
    float q = a * a + c * c;
    #pragma unroll
    for (int m = 32; m; m >>= 1) {
        s += __shfl_xor(s, m);
        q += __shfl_xor(q, m);
    }
    mean = s * (1.0f / 128.0f);
    float var = q * (1.0f / 128.0f) - mean * mean;
    rs = rsqrtf(var + 1e-5f);
}

// ---------------------------------------------------------------------------
// Setup kernel (512 thr):
//   blocks [0,256):   input MLP, 8 rows each  -> h0
//   blocks [256,264): normalize emb -> nep (bf16-packed pairs)
//   blocks [264,296): pack edge_cat: catp[jb*256+i] = uint2 of cats (i, jb*8..+7)
__global__ __launch_bounds__(512) void k_setup(
    const float* __restrict__ x, const float* __restrict__ emb,
    const float* __restrict__ inW1, const float* __restrict__ inb1,
    const float* __restrict__ ing1, const float* __restrict__ inbt1,
    const float* __restrict__ inW2, const float* __restrict__ inb2,
    const float* __restrict__ ing2, const float* __restrict__ inbt2,
    const int* __restrict__ ecat,
    unsigned* __restrict__ nep, uint2* __restrict__ catp, float* __restrict__ h0)
{
    __shared__ __align__(16) float sV[8][128];
    __shared__ __align__(16) float sH1[8][128];
    __shared__ __align__(16) float sA[4][8][128];
    __shared__ __align__(16) uint4 sH1T[128];

    const int blk = blockIdx.x;
    const int t = threadIdx.x;
    const int w = t >> 6, lane = t & 63;

    if (blk < 256) {
        const int row0 = blk * 8;
        for (int item = t; item < 1024; item += 512) {
            int r = item >> 7, d2 = item & 127;
            int row = row0 + r;
            float x0 = x[row * 2 + 0], x1 = x[row * 2 + 1];
            sV[r][d2] = fmaf(x0, inW1[d2], fmaf(x1, inW1[128 + d2], inb1[d2]));
        }
        __syncthreads();
        {
            float a = sV[w][lane], c = sV[w][lane + 64];
            float mean, rs; ln_stats(a, c, mean, rs);
            sH1[w][lane]      = fmaxf((a - mean) * rs * ing1[lane]      + inbt1[lane],      0.f);
            sH1[w][lane + 64] = fmaxf((c - mean) * rs * ing1[lane + 64] + inbt1[lane + 64], 0.f);
        }
        __syncthreads();
        {
            int kd = t & 127, wr = t >> 7;
            ((unsigned*)sH1T)[kd * 4 + wr] = pack_bf16(sH1[2 * wr][kd], sH1[2 * wr + 1][kd]);
        }
        __syncthreads();
        {
            const int dd = t & 127, ks = t >> 7;
            float a8[8] = {0.f,0.f,0.f,0.f,0.f,0.f,0.f,0.f};
            #pragma unroll 8
            for (int k = 0; k < 32; ++k) {
                int kk = ks * 32 + k;
                uint4 a = sH1T[kk];
                float wv = inW2[kk * 128 + dd];
                a8[0] = fmaf(bf_lo(a.x), wv, a8[0]);
                a8[1] = fmaf(bf_hi(a.x), wv, a8[1]);
                a8[2] = fmaf(bf_lo(a.y), wv, a8[2]);
                a8[3] = fmaf(bf_hi(a.y), wv, a8[3]);
                a8[4] = fmaf(bf_lo(a.z), wv, a8[4]);
                a8[5] = fmaf(bf_hi(a.z), wv, a8[5]);
                a8[6] = fmaf(bf_lo(a.w), wv, a8[6]);
                a8[7] = fmaf(bf_hi(a.w), wv, a8[7]);
            }
            #pragma unroll
            for (int r = 0; r < 8; ++r) sA[ks][r][dd] = a8[r];
        }
        __syncthreads();
        for (int item = t; item < 1024; item += 512) {
            int r = item >> 7, d2 = item & 127;
            sV[r][d2] = inb2[d2] + sA[0][r][d2] + sA[1][r][d2] + sA[2][r][d2] + sA[3][r][d2];
        }
        __syncthreads();
        {
            float a = sV[w][lane], c = sV[w][lane + 64];
            float mean, rs; ln_stats(a, c, mean, rs);
            int row = row0 + w;
            h0[row * HID + lane]      = (a - mean) * rs * ing2[lane]      + inbt2[lane];
            h0[row * HID + lane + 64] = (c - mean) * rs * ing2[lane + 64] + inbt2[lane + 64];
        }
    } else if (blk < 264) {
        int r = (blk - 256) * 8 + w;
        float2 em = *(const float2*)(emb + r * 128 + 2 * lane);
        float q = em.x * em.x + em.y * em.y;
        #pragma unroll
        for (int m = 32; m; m >>= 1) q += __shfl_xor(q, m);
        float cn = sqrtf(q);
        if (cn == 0.f) cn = 1e-8f;
        float sc = fminf(1.0f, 1.0f / cn);
        nep[r * 64 + lane] = pack_bf16(em.x * sc, em.y * sc);
    } else {
        int jb = blk - 264;
        if (t < 256) {
            const int* p = ecat + t * NN + jb * 8;
            int4 c0 = *(const int4*)p;
            int4 c1 = *(const int4*)(p + 4);
            unsigned lo = (unsigned)c0.x | ((unsigned)c0.y << 8) |
                          ((unsigned)c0.z << 16) | ((unsigned)c0.w << 24);
            unsigned hi = (unsigned)c1.x | ((unsigned)c1.y << 8) |
                          ((unsigned)c1.z << 16) | ((unsigned)c1.w << 24);
            catp[jb * 256 + t] = make_uint2(lo, hi);
        }
    }
}

// ---------------------------------------------------------------------------
// One GINE layer. Block (b, jb) owns dst rows jb*8..jb*8+7 of item b.
// grid = 256 x 1024 threads -> 16 waves/CU (4/SIMD) in ONE block: latency
// hiding without multi-block residency gambles. LDS ~93 KB (<160 KB/CU).
__global__ __launch_bounds__(1024) void k_layer(
    const float* __restrict__ h_old, float* __restrict__ h_new,
    const uint4* __restrict__ nep4, const uint2* __restrict__ catp,
    const float* __restrict__ W1, const float* __restrict__ b1,
    const float* __restrict__ g1, const float* __restrict__ bt1,
    const float* __restrict__ W2, const float* __restrict__ b2,
    const float* __restrict__ g2, const float* __restrict__ bt2,
    const float* __restrict__ epsp,
    const float* __restrict__ lng, const float* __restrict__ lnb,
    const float* __restrict__ outW, const float* __restrict__ outb,
    float* __restrict__ dout, int isLast)
{
    __shared__ __align__(16) uint4 sNe4[NCATS * 17];    // 17408 B bf16 ne (padded)
    __shared__ __align__(16) float sPart[16 * 8 * 128]; // 64 KB agg / 32 KB GEMM partials
    __shared__ __align__(16) uint2 sCat[256];           // 2 KB
    __shared__ __align__(16) uint4 sUT[128];            // 2 KB transposed bf16 u
    __shared__ __align__(16) float sH1[8][128];         // 4 KB
    __shared__ __align__(16) uint4 sH1T[128];           // 2 KB   (total 93184 B)

    const int t  = threadIdx.x;
    const int b  = blockIdx.x >> 5;
    const int jb = blockIdx.x & 31;
    const int w  = t >> 6, lane = t & 63;
    const float* hb = h_old + (size_t)b * NN * HID;
    const uint2* sNe2 = (const uint2*)sNe4;

    // ---- stage bf16 ne (padded rows) + packed cats (1024-exact) ----
    sNe4[(t >> 4) * 17 + (t & 15)] = nep4[t];
    if (t < 256) sCat[t] = catp[jb * 256 + t];
    __syncthreads();

    // ---- aggregation: thread = (4 dims dg, 8 srcs ig); 8 dst rows in regs ----
    const int dg = t & 31;   // dims [dg*4, dg*4+4)
    const int ig = t >> 5;   // srcs [ig*8, ig*8+8), 32 groups
    float acc[8][4];
    #pragma unroll
    for (int k = 0; k < 8; ++k)
        #pragma unroll
        for (int d = 0; d < 4; ++d) acc[k][d] = 0.f;

    #pragma unroll
    for (int n = 0; n < 8; ++n) {
        int i = ig * 8 + n;
        float4 hv = *(const float4*)(hb + i * HID + dg * 4);
        uint2 c8 = sCat[i];
        #pragma unroll
        for (int k = 0; k < 8; ++k) {
            unsigned c = ((k < 4 ? (c8.x >> (8 * k)) : (c8.y >> (8 * (k - 4)))) & 255u);
            uint2 nv = sNe2[c * 34 + dg];
            acc[k][0] += fmaxf(hv.x + bf_lo(nv.x), 0.f);
            acc[k][1] += fmaxf(hv.y + bf_hi(nv.x), 0.f);
            acc[k][2] += fmaxf(hv.z + bf_lo(nv.y), 0.f);
            acc[k][3] += fmaxf(hv.w + bf_hi(nv.y), 0.f);
        }
    }
    // merge the wave's two src subgroups (lane ^ 32) -> group = wave (16 groups)
    #pragma unroll
    for (int k = 0; k < 8; ++k)
        #pragma unroll
        for (int d = 0; d < 4; ++d)
            acc[k][d] += __shfl_xor(acc[k][d], 32);
    // half-wave 0 stores rows 0..3, half-wave 1 stores rows 4..7
    {
        int hw = (t >> 5) & 1;
        #pragma unroll
        for (int q = 0; q < 4; ++q) {
            int r = hw * 4 + q;
            *(float4*)&sPart[(w * 8 + r) * 128 + dg * 4] =
                make_float4(acc[r][0], acc[r][1], acc[r][2], acc[r][3]);
        }
    }
    __syncthreads();

    // ---- combine 16 partials + u=(1+eps)h + bf16 pack (512 active) ----
    if (t < 512) {
        int dim = t & 127, p = t >> 7;            // rows 2p, 2p+1
        const float eps1 = 1.0f + epsp[0];
        int r0 = 2 * p, r1 = 2 * p + 1;
        float u0 = eps1 * hb[(jb * 8 + r0) * HID + dim];
        float u1 = eps1 * hb[(jb * 8 + r1) * HID + dim];
        #pragma unroll
        for (int g = 0; g < 16; ++g) {
            u0 += sPart[(g * 8 + r0) * 128 + dim];
            u1 += sPart[(g * 8 + r1) * 128 + dim];
        }
        ((unsigned*)sUT)[dim * 4 + p] = pack_bf16(u0, u1);
    }
    __syncthreads();

    // ---- GEMM1: k-split 8 (1024-exact), transposed-bf16 A ----
    {
        const int dd = t & 127, ks = t >> 7;
        float a8[8] = {0.f,0.f,0.f,0.f,0.f,0.f,0.f,0.f};
        #pragma unroll 8
        for (int k = 0; k < 16; ++k) {
            int kk = ks * 16 + k;
            uint4 ax = sUT[kk];
            float wv = W1[kk * 128 + dd];
            a8[0] = fmaf(bf_lo(ax.x), wv, a8[0]);
            a8[1] = fmaf(bf_hi(ax.x), wv, a8[1]);
            a8[2] = fmaf(bf_lo(ax.y), wv, a8[2]);
            a8[3] = fmaf(bf_hi(ax.y), wv, a8[3]);
            a8[4] = fmaf(bf_lo(ax.z), wv, a8[4]);
            a8[5] = fmaf(bf_hi(ax.z), wv, a8[5]);
            a8[6] = fmaf(bf_lo(ax.w), wv, a8[6]);
            a8[7] = fmaf(bf_hi(ax.w), wv, a8[7]);
        }
        #pragma unroll
        for (int r = 0; r < 8; ++r) sPart[(ks * 8 + r) * 128 + dd] = a8[r];
    }
    __syncthreads();

    // ---- LN1 + relu (bias + 8-way k-split sum folded); wave w -> row w ----
    if (w < 8) {
        float aa = b1[lane], cc = b1[lane + 64];
        #pragma unroll
        for (int ks = 0; ks < 8; ++ks) {
            aa += sPart[(ks * 8 + w) * 128 + lane];
            cc += sPart[(ks * 8 + w) * 128 + lane + 64];
        }
        float mean, rs; ln_stats(aa, cc, mean, rs);
        sH1[w][lane]      = fmaxf((aa - mean) * rs * g1[lane]      + bt1[lane],      0.f);
        sH1[w][lane + 64] = fmaxf((cc - mean) * rs * g1[lane + 64] + bt1[lane + 64], 0.f);
    }
    __syncthreads();

    // ---- pack h1 transposed bf16 (512 active) ----
    if (t < 512) {
        int dim = t & 127, p = t >> 7;
        ((unsigned*)sH1T)[dim * 4 + p] = pack_bf16(sH1[2 * p][dim], sH1[2 * p + 1][dim]);
    }
    __syncthreads();

    // ---- GEMM2 ----
    {
        const int dd = t & 127, ks = t >> 7;
        float a8[8] = {0.f,0.f,0.f,0.f,0.f,0.f,0.f,0.f};
        #pragma unroll 8
        for (int k = 0; k < 16; ++k) {
            int kk = ks * 16 + k;
            uint4 ax = sH1T[kk];
            float wv = W2[kk * 128 + dd];
            a8[0] = fmaf(bf_lo(ax.x), wv, a8[0]);
            a8[1] = fmaf(bf_hi(ax.x), wv, a8[1]);
            a8[2] = fmaf(bf_lo(ax.y), wv, a8[2]);
            a8[3] = fmaf(bf_hi(ax.y), wv, a8[3]);
            a8[4] = fmaf(bf_lo(ax.z), wv, a8[4]);
            a8[5] = fmaf(bf_hi(ax.z), wv, a8[5]);
            a8[6] = fmaf(bf_lo(ax.w), wv, a8[6]);
            a8[7] = fmaf(bf_hi(ax.w), wv, a8[7]);
        }
        #pragma unroll
        for (int r = 0; r < 8; ++r) sPart[(ks * 8 + r) * 128 + dd] = a8[r];
    }
    __syncthreads();

    // ---- LN2 (bias+sum folded) -> LN3 + relu + residual -> store ----
    if (w < 8) {
        float aa = b2[lane], cc = b2[lane + 64];
        #pragma unroll
        for (int ks = 0; ks < 8; ++ks) {
            aa += sPart[(ks * 8 + w) * 128 + lane];
            cc += sPart[(ks * 8 + w) * 128 + lane + 64];
        }
        float mean, rs; ln_stats(aa, cc, mean, rs);
        float y1 = (aa - mean) * rs * g2[lane]      + bt2[lane];
        float y2 = (cc - mean) * rs * g2[lane + 64] + bt2[lane + 64];

        float mean3, rs3; ln_stats(y1, y2, mean3, rs3);
        int row = jb * 8 + w;
        int grow = b * NN + row;
        float ho1 = hb[row * HID + lane], ho2 = hb[row * HID + lane + 64];
        float z1 = fmaxf((y1 - mean3) * rs3 * lng[lane]      + lnb[lane],      0.f) + ho1;
        float z2 = fmaxf((y2 - mean3) * rs3 * lng[lane + 64] + lnb[lane + 64], 0.f) + ho2;

        if (!isLast) {
            h_new[(size_t)grow * HID + lane]      = z1;
            h_new[(size_t)grow * HID + lane + 64] = z2;
        } else {
            #pragma unroll
            for (int ccx = 0; ccx < 3; ++ccx) {
                float p = z1 * outW[lane * 3 + ccx] + z2 * outW[(lane + 64) * 3 + ccx];
                #pragma unroll
                for (int m = 32; m; m >>= 1) p += __shfl_xor(p, m);
                if (lane == 0) dout[grow * 3 + ccx] = p + outb[ccx];
            }
        }
    }
}

// ---------------------------------------------------------------------------
extern "C" void kernel_launch(void* const* d_in, const int* in_sizes, int n_in,
                              void* d_out, int out_size, void* d_ws, size_t ws_size,
                              hipStream_t stream) {
    const float* x     = (const float*)d_in[0];
    const float* emb   = (const float*)d_in[1];
    const float* inW1  = (const float*)d_in[2];
    const float* inb1  = (const float*)d_in[3];
    const float* ing1  = (const float*)d_in[4];
    const float* inbt1 = (const float*)d_in[5];
    const float* inW2  = (const float*)d_in[6];
    const float* inb2  = (const float*)d_in[7];
    const float* ing2  = (const float*)d_in[8];
    const float* inbt2 = (const float*)d_in[9];
    const float* cW1   = (const float*)d_in[10];
    const float* cb1   = (const float*)d_in[11];
    const float* cg1   = (const float*)d_in[12];
    const float* cbt1  = (const float*)d_in[13];
    const float* cW2   = (const float*)d_in[14];
    const float* cb2   = (const float*)d_in[15];
    const float* cg2   = (const float*)d_in[16];
    const float* cbt2  = (const float*)d_in[17];
    const float* ceps  = (const float*)d_in[18];
    const float* lng   = (const float*)d_in[19];
    const float* lnb   = (const float*)d_in[20];
    const float* outW  = (const float*)d_in[21];
    const float* outb  = (const float*)d_in[22];
    const int*   ecat  = (const int*)d_in[25];

    float* ws      = (float*)d_ws;
    unsigned* nep  = (unsigned*)ws;             // 4096 u32 (16 KB bf16 ne)
    uint2* catp    = (uint2*)(ws + 4096);       // 8192 uint2
    float* hA   = ws + 4096 + 16384;            // B*N*HID
    float* hB   = hA + BB * NN * HID;
    float* out  = (float*)d_out;

    k_setup<<<296, 512, 0, stream>>>(x, emb, inW1, inb1, ing1, inbt1,
                                     inW2, inb2, ing2, inbt2, ecat, nep, catp, hA);

    for (int l = 0; l < 4; ++l) {
        const float* ho = (l & 1) ? hB : hA;
        float*       hn = (l & 1) ? hA : hB;
        k_layer<<<256, 1024, 0, stream>>>(
            ho, hn, (const uint4*)nep, catp,
            cW1 + l * HID * HID, cb1 + l * HID, cg1 + l * HID, cbt1 + l * HID,
            cW2 + l * HID * HID, cb2 + l * HID, cg2 + l * HID, cbt2 + l * HID,
            ceps + l, lng + l * HID, lnb + l * HID,
            outW, outb, out, (l == 3) ? 1 : 0);
    }
}